// Round 1
// baseline (861.711 us; speedup 1.0000x reference)
//
#include <hip/hip_runtime.h>
#include <hip/hip_fp16.h>

#define N_NODES 50000
#define N_EDGES 800000
// F_KEY_NFEAT = 64, scale = 1/sqrt(64) = 0.125
// fiber2head: head h of a 64-float row = [f0[2h], f0[2h+1], f1[6h..6h+5]]

struct alignas(16) H8 { __half h[8]; };

// ---------------- 1. col-degree histogram (int atomics only) ----------------
__global__ __launch_bounds__(256) void k_hist(const int* __restrict__ ei,
                                              int* __restrict__ cnt_c)
{
    int e = blockIdx.x * blockDim.x + threadIdx.x;
    if (e >= N_EDGES) return;
    atomicAdd(cnt_c + ei[N_EDGES + e], 1);
}

// ---------------- 2. exclusive scan of col-degree array ----------------
#define SCAN_T 1024
#define SCAN_I 8
__global__ __launch_bounds__(SCAN_T) void k_scan(int* cnt, int* off)
{
    __shared__ int sm[SCAN_T];
    __shared__ int carry_s;
    const int n = N_NODES;
    if (threadIdx.x == 0) carry_s = 0;
    __syncthreads();
    for (int base = 0; base < n; base += SCAN_T * SCAN_I) {
        int idx0 = base + threadIdx.x * SCAN_I;
        int v[SCAN_I];
        int sum = 0;
        #pragma unroll
        for (int j = 0; j < SCAN_I; ++j) {
            int i = idx0 + j;
            v[j] = (i < n) ? cnt[i] : 0;
            sum += v[j];
        }
        sm[threadIdx.x] = sum;
        __syncthreads();
        for (int d = 1; d < SCAN_T; d <<= 1) {
            int t = (threadIdx.x >= d) ? sm[threadIdx.x - d] : 0;
            __syncthreads();
            sm[threadIdx.x] += t;
            __syncthreads();
        }
        int excl_thread = sm[threadIdx.x] - sum;
        int carry = carry_s;
        int run = carry + excl_thread;
        #pragma unroll
        for (int j = 0; j < SCAN_I; ++j) {
            int i = idx0 + j;
            if (i < n) { off[i] = run; cnt[i] = run; }  // cnt becomes fill cursor
            run += v[j];
        }
        __syncthreads();
        if (threadIdx.x == SCAN_T - 1) carry_s = carry + sm[threadIdx.x];
        __syncthreads();
    }
    if (threadIdx.x == 0) off[n] = carry_s;
}

// ---------------- 3. logits + exp (f16) + s atomics + col-CSR fill ----------------
__global__ __launch_bounds__(256) void k_logits_fill(
    const float* __restrict__ k0, const float* __restrict__ k1,
    const float* __restrict__ q0, const float* __restrict__ q1,
    const int* __restrict__ ei, __half* __restrict__ e_buf,
    float* __restrict__ s,
    int* __restrict__ cur_c, int* __restrict__ eid_c)
{
    int e = blockIdx.x * blockDim.x + threadIdx.x;
    if (e >= N_EDGES) return;
    int row = ei[e];
    int col = ei[N_EDGES + e];

    const float4* k0v = (const float4*)(k0 + (size_t)e   * 16);
    const float4* q0v = (const float4*)(q0 + (size_t)col * 16);
    const float4* k1v = (const float4*)(k1 + (size_t)e   * 48);
    const float4* q1v = (const float4*)(q1 + (size_t)col * 48);

    float acc[8];
    #pragma unroll
    for (int h = 0; h < 8; ++h) acc[h] = 0.f;

    #pragma unroll
    for (int i = 0; i < 4; ++i) {
        float4 kv = k0v[i];
        float4 qv = q0v[i];
        acc[(4*i+0)/2] += kv.x * qv.x;
        acc[(4*i+1)/2] += kv.y * qv.y;
        acc[(4*i+2)/2] += kv.z * qv.z;
        acc[(4*i+3)/2] += kv.w * qv.w;
    }
    #pragma unroll
    for (int j = 0; j < 12; ++j) {
        float4 kv = k1v[j];
        float4 qv = q1v[j];
        acc[(4*j+0)/6] += kv.x * qv.x;
        acc[(4*j+1)/6] += kv.y * qv.y;
        acc[(4*j+2)/6] += kv.z * qv.z;
        acc[(4*j+3)/6] += kv.w * qv.w;
    }

    H8 pack;
    #pragma unroll
    for (int h = 0; h < 8; ++h) {
        __half hv = __float2half(__expf(acc[h] * 0.125f));
        pack.h[h] = hv;
        // sum the SAME half-rounded values k_out will read -> numerics match old k_s path
        atomicAdd(s + (size_t)row * 8 + h, __half2float(hv));
    }
    *(H8*)(e_buf + (size_t)e * 8) = pack;

    int pc = atomicAdd(cur_c + col, 1);
    eid_c[pc] = e;
}

// ---------------- 4. reciprocal of softmax denominator ----------------
__global__ __launch_bounds__(256) void k_rs(const float* __restrict__ s,
                                            float* __restrict__ rs)
{
    int i = blockIdx.x * blockDim.x + threadIdx.x;
    if (i < N_NODES * 8) rs[i] = 1.0f / s[i];
}

// ---------------- 5. output via col-CSR gather: 1 wave/node, lane=feature ----------------
// 4x unrolled: 4 independent eid->data chains in flight per wave (MLP).
__global__ __launch_bounds__(256) void k_out(
    const float* __restrict__ v0, const float* __restrict__ v1,
    const int* __restrict__ ei, const __half* __restrict__ e_buf,
    const float* __restrict__ rs,
    const int* __restrict__ off_c, const int* __restrict__ eid_c,
    float* __restrict__ out0, float* __restrict__ out1)
{
    int wave = (blockIdx.x * blockDim.x + threadIdx.x) >> 6;
    int lane = threadIdx.x & 63;
    if (wave >= N_NODES) return;
    bool is0 = lane < 16;
    int f1 = lane - 16;                       // index into the 48-float v1 row
    int head = is0 ? (lane >> 1) : (f1 / 6);
    const float* __restrict__ vbase = is0 ? (v0 + lane) : (v1 + f1);
    int vstride = is0 ? 16 : 48;

    int beg = off_c[wave], end = off_c[wave + 1];
    float acc = 0.f;
    int i = beg;
    for (; i + 4 <= end; i += 4) {
        int e0 = eid_c[i + 0];                // 4 independent chains
        int e1 = eid_c[i + 1];
        int e2 = eid_c[i + 2];
        int e3 = eid_c[i + 3];
        int r0 = ei[e0], r1 = ei[e1], r2 = ei[e2], r3 = ei[e3];
        float w0 = vbase[(size_t)e0 * vstride];
        float w1 = vbase[(size_t)e1 * vstride];
        float w2 = vbase[(size_t)e2 * vstride];
        float w3 = vbase[(size_t)e3 * vstride];
        float a0 = __half2float(e_buf[(size_t)e0 * 8 + head]) * rs[(size_t)r0 * 8 + head];
        float a1 = __half2float(e_buf[(size_t)e1 * 8 + head]) * rs[(size_t)r1 * 8 + head];
        float a2 = __half2float(e_buf[(size_t)e2 * 8 + head]) * rs[(size_t)r2 * 8 + head];
        float a3 = __half2float(e_buf[(size_t)e3 * 8 + head]) * rs[(size_t)r3 * 8 + head];
        acc += a0 * w0;
        acc += a1 * w1;
        acc += a2 * w2;
        acc += a3 * w3;
    }
    for (; i < end; ++i) {
        int e0 = eid_c[i];
        int r0 = ei[e0];
        acc += __half2float(e_buf[(size_t)e0 * 8 + head])
             * rs[(size_t)r0 * 8 + head]
             * vbase[(size_t)e0 * vstride];
    }
    if (is0) out0[(size_t)wave * 16 + lane] = acc;
    else     out1[(size_t)wave * 48 + f1]   = acc;
}

extern "C" void kernel_launch(void* const* d_in, const int* in_sizes, int n_in,
                              void* d_out, int out_size, void* d_ws, size_t ws_size,
                              hipStream_t stream) {
    const float* v0 = (const float*)d_in[0];
    const float* v1 = (const float*)d_in[1];
    const float* k0 = (const float*)d_in[2];
    const float* k1 = (const float*)d_in[3];
    const float* q0 = (const float*)d_in[4];
    const float* q1 = (const float*)d_in[5];
    const int*   ei = (const int*)d_in[6];

    float* out0 = (float*)d_out;                      // N*16 floats
    float* out1 = out0 + (size_t)N_NODES * 16;        // N*48 floats

    // ---- workspace layout (bytes, all 16B-aligned), total ~19.6 MB ----
    char* ws = (char*)d_ws;
    float*  s     = (float*) (ws + 0);                // N*8*4   = 1,600,000
    int*    cnt_c = (int*)   (ws + 1600000);          // N*4     = 200,000 (adjacent to s: one memset)
    int*    off_c = (int*)   (ws + 1800000);          // (N+1)*4 -> pad 200,016
    int*    eid_c = (int*)   (ws + 2000016);          // E*4     = 3,200,000
    __half* e_buf = (__half*)(ws + 5200016);          // E*8*2   = 12,800,000
    float*  rs    = (float*) (ws + 18000016);         // N*8*4   = 1,600,000

    // zero s + cnt_c in one shot (adjacent)
    hipMemsetAsync(ws, 0, 1800000, stream);

    const int block = 256;
    const int gridE = (N_EDGES + block - 1) / block;

    k_hist<<<gridE, block, 0, stream>>>(ei, cnt_c);
    k_scan<<<1, SCAN_T, 0, stream>>>(cnt_c, off_c);
    k_logits_fill<<<gridE, block, 0, stream>>>(k0, k1, q0, q1, ei, e_buf,
                                               s, cnt_c, eid_c);
    k_rs<<<(N_NODES * 8 + block - 1) / block, block, 0, stream>>>(s, rs);
    k_out<<<(N_NODES * 64 + block - 1) / block, block, 0, stream>>>(
        v0, v1, ei, e_buf, rs, off_c, eid_c, out0, out1);
}

// Round 2
// 734.223 us; speedup vs baseline: 1.1736x; 1.1736x over previous
//
#include <hip/hip_runtime.h>
#include <hip/hip_fp16.h>

#define N_NODES 50000
#define N_EDGES 800000
// F_KEY_NFEAT = 64, scale = 1/sqrt(64) = 0.125
// fiber2head: head h of a 64-float row = [f0[2h], f0[2h+1], f1[6h..6h+5]]

struct alignas(16) H8 { __half h[8]; };

// ---------------- 1. degree histograms (int atomics only) ----------------
__global__ __launch_bounds__(256) void k_hist(const int* __restrict__ ei,
                                              int* __restrict__ cnt_r,
                                              int* __restrict__ cnt_c)
{
    int e = blockIdx.x * blockDim.x + threadIdx.x;
    if (e >= N_EDGES) return;
    atomicAdd(cnt_r + ei[e], 1);
    atomicAdd(cnt_c + ei[N_EDGES + e], 1);
}

// ---------------- 2. exclusive scan of both degree arrays ----------------
#define SCAN_T 1024
#define SCAN_I 8
__global__ __launch_bounds__(SCAN_T) void k_scan2(int* cnt_r, int* off_r,
                                                  int* cnt_c, int* off_c)
{
    __shared__ int sm[SCAN_T];
    __shared__ int carry_s;
    const int n = N_NODES;
    for (int pass = 0; pass < 2; ++pass) {
        int* cnt = pass ? cnt_c : cnt_r;
        int* off = pass ? off_c : off_r;
        if (threadIdx.x == 0) carry_s = 0;
        __syncthreads();
        for (int base = 0; base < n; base += SCAN_T * SCAN_I) {
            int idx0 = base + threadIdx.x * SCAN_I;
            int v[SCAN_I];
            int sum = 0;
            #pragma unroll
            for (int j = 0; j < SCAN_I; ++j) {
                int i = idx0 + j;
                v[j] = (i < n) ? cnt[i] : 0;
                sum += v[j];
            }
            sm[threadIdx.x] = sum;
            __syncthreads();
            for (int d = 1; d < SCAN_T; d <<= 1) {
                int t = (threadIdx.x >= d) ? sm[threadIdx.x - d] : 0;
                __syncthreads();
                sm[threadIdx.x] += t;
                __syncthreads();
            }
            int excl_thread = sm[threadIdx.x] - sum;
            int carry = carry_s;
            int run = carry + excl_thread;
            #pragma unroll
            for (int j = 0; j < SCAN_I; ++j) {
                int i = idx0 + j;
                if (i < n) { off[i] = run; cnt[i] = run; }  // cnt becomes fill cursor
                run += v[j];
            }
            __syncthreads();
            if (threadIdx.x == SCAN_T - 1) carry_s = carry + sm[threadIdx.x];
            __syncthreads();
        }
        if (threadIdx.x == 0) off[n] = carry_s;
        __syncthreads();
    }
}

// ---------------- 3. logits + exp (f16) + dual CSR fill (int atomics only) ----------------
__global__ __launch_bounds__(256) void k_logits_fill(
    const float* __restrict__ k0, const float* __restrict__ k1,
    const float* __restrict__ q0, const float* __restrict__ q1,
    const int* __restrict__ ei, __half* __restrict__ e_buf,
    int* __restrict__ cur_r, int* __restrict__ cur_c,
    int* __restrict__ eid_r, int* __restrict__ eid_c)
{
    int e = blockIdx.x * blockDim.x + threadIdx.x;
    if (e >= N_EDGES) return;
    int row = ei[e];
    int col = ei[N_EDGES + e];

    // issue CSR-cursor atomics early: latency overlaps the 16 k/q loads below
    int pr = atomicAdd(cur_r + row, 1);
    int pc = atomicAdd(cur_c + col, 1);

    const float4* k0v = (const float4*)(k0 + (size_t)e   * 16);
    const float4* q0v = (const float4*)(q0 + (size_t)col * 16);
    const float4* k1v = (const float4*)(k1 + (size_t)e   * 48);
    const float4* q1v = (const float4*)(q1 + (size_t)col * 48);

    float acc[8];
    #pragma unroll
    for (int h = 0; h < 8; ++h) acc[h] = 0.f;

    #pragma unroll
    for (int i = 0; i < 4; ++i) {
        float4 kv = k0v[i];
        float4 qv = q0v[i];
        acc[(4*i+0)/2] += kv.x * qv.x;
        acc[(4*i+1)/2] += kv.y * qv.y;
        acc[(4*i+2)/2] += kv.z * qv.z;
        acc[(4*i+3)/2] += kv.w * qv.w;
    }
    #pragma unroll
    for (int j = 0; j < 12; ++j) {
        float4 kv = k1v[j];
        float4 qv = q1v[j];
        acc[(4*j+0)/6] += kv.x * qv.x;
        acc[(4*j+1)/6] += kv.y * qv.y;
        acc[(4*j+2)/6] += kv.z * qv.z;
        acc[(4*j+3)/6] += kv.w * qv.w;
    }

    H8 pack;
    #pragma unroll
    for (int h = 0; h < 8; ++h) pack.h[h] = __float2half(__expf(acc[h] * 0.125f));
    *(H8*)(e_buf + (size_t)e * 8) = pack;

    eid_r[pr] = e;
    eid_c[pc] = e;
}

// ---------------- 4. softmax denominator reciprocal via row-CSR gather ----------------
// thread = (node, head); 4x unrolled edge loop for memory-level parallelism.
__global__ __launch_bounds__(256) void k_s(const __half* __restrict__ e_buf,
                                           const int* __restrict__ off_r,
                                           const int* __restrict__ eid_r,
                                           float* __restrict__ rs)
{
    int t = blockIdx.x * blockDim.x + threadIdx.x;
    int node = t >> 3;
    int h = t & 7;
    if (node >= N_NODES) return;
    int beg = off_r[node], end = off_r[node + 1];
    float acc = 0.f;
    int i = beg;
    for (; i + 4 <= end; i += 4) {
        int e0 = eid_r[i + 0];
        int e1 = eid_r[i + 1];
        int e2 = eid_r[i + 2];
        int e3 = eid_r[i + 3];
        float x0 = __half2float(e_buf[(size_t)e0 * 8 + h]);
        float x1 = __half2float(e_buf[(size_t)e1 * 8 + h]);
        float x2 = __half2float(e_buf[(size_t)e2 * 8 + h]);
        float x3 = __half2float(e_buf[(size_t)e3 * 8 + h]);
        acc += x0; acc += x1; acc += x2; acc += x3;
    }
    for (; i < end; ++i) {
        acc += __half2float(e_buf[(size_t)eid_r[i] * 8 + h]);
    }
    rs[(size_t)node * 8 + h] = 1.0f / acc;   // inf only for edge-less rows, never read
}

// ---------------- 5. output via col-CSR gather: 1 wave/node, lane=feature ----------------
// 4x unrolled: 4 independent eid->data chains in flight per wave (MLP).
__global__ __launch_bounds__(256) void k_out(
    const float* __restrict__ v0, const float* __restrict__ v1,
    const int* __restrict__ ei, const __half* __restrict__ e_buf,
    const float* __restrict__ rs,
    const int* __restrict__ off_c, const int* __restrict__ eid_c,
    float* __restrict__ out0, float* __restrict__ out1)
{
    int wave = (blockIdx.x * blockDim.x + threadIdx.x) >> 6;
    int lane = threadIdx.x & 63;
    if (wave >= N_NODES) return;
    bool is0 = lane < 16;
    int f1 = lane - 16;                       // index into the 48-float v1 row
    int head = is0 ? (lane >> 1) : (f1 / 6);
    const float* __restrict__ vbase = is0 ? (v0 + lane) : (v1 + f1);
    int vstride = is0 ? 16 : 48;

    int beg = off_c[wave], end = off_c[wave + 1];
    float acc = 0.f;
    int i = beg;
    for (; i + 4 <= end; i += 4) {
        int e0 = eid_c[i + 0];                // 4 independent chains
        int e1 = eid_c[i + 1];
        int e2 = eid_c[i + 2];
        int e3 = eid_c[i + 3];
        int r0 = ei[e0], r1 = ei[e1], r2 = ei[e2], r3 = ei[e3];
        float w0 = vbase[(size_t)e0 * vstride];
        float w1 = vbase[(size_t)e1 * vstride];
        float w2 = vbase[(size_t)e2 * vstride];
        float w3 = vbase[(size_t)e3 * vstride];
        float a0 = __half2float(e_buf[(size_t)e0 * 8 + head]) * rs[(size_t)r0 * 8 + head];
        float a1 = __half2float(e_buf[(size_t)e1 * 8 + head]) * rs[(size_t)r1 * 8 + head];
        float a2 = __half2float(e_buf[(size_t)e2 * 8 + head]) * rs[(size_t)r2 * 8 + head];
        float a3 = __half2float(e_buf[(size_t)e3 * 8 + head]) * rs[(size_t)r3 * 8 + head];
        acc += a0 * w0;
        acc += a1 * w1;
        acc += a2 * w2;
        acc += a3 * w3;
    }
    for (; i < end; ++i) {
        int e0 = eid_c[i];
        int r0 = ei[e0];
        acc += __half2float(e_buf[(size_t)e0 * 8 + head])
             * rs[(size_t)r0 * 8 + head]
             * vbase[(size_t)e0 * vstride];
    }
    if (is0) out0[(size_t)wave * 16 + lane] = acc;
    else     out1[(size_t)wave * 48 + f1]   = acc;
}

extern "C" void kernel_launch(void* const* d_in, const int* in_sizes, int n_in,
                              void* d_out, int out_size, void* d_ws, size_t ws_size,
                              hipStream_t stream) {
    const float* v0 = (const float*)d_in[0];
    const float* v1 = (const float*)d_in[1];
    const float* k0 = (const float*)d_in[2];
    const float* k1 = (const float*)d_in[3];
    const float* q0 = (const float*)d_in[4];
    const float* q1 = (const float*)d_in[5];
    const int*   ei = (const int*)d_in[6];

    float* out0 = (float*)d_out;                      // N*16 floats
    float* out1 = out0 + (size_t)N_NODES * 16;        // N*48 floats

    // ---- workspace layout (bytes, all 16B-aligned), total ~21.6 MB ----
    char* ws = (char*)d_ws;
    int*    cnt_r = (int*)   (ws + 0);                // N*4     = 200,000
    int*    cnt_c = (int*)   (ws + 200000);           // N*4     = 200,000 (adjacent: one memset)
    int*    off_r = (int*)   (ws + 400000);           // (N+1)*4 -> pad 200,016
    int*    off_c = (int*)   (ws + 600016);           // pad 200,016
    int*    eid_r = (int*)   (ws + 800032);           // E*4     = 3,200,000
    int*    eid_c = (int*)   (ws + 4000032);          // E*4     = 3,200,000
    __half* e_buf = (__half*)(ws + 7200032);          // E*8*2   = 12,800,000
    float*  rs    = (float*) (ws + 20000032);         // N*8*4   = 1,600,000

    // zero both degree arrays in one shot (adjacent)
    hipMemsetAsync(cnt_r, 0, 400000, stream);

    const int block = 256;
    const int gridE = (N_EDGES + block - 1) / block;

    k_hist<<<gridE, block, 0, stream>>>(ei, cnt_r, cnt_c);
    k_scan2<<<1, SCAN_T, 0, stream>>>(cnt_r, off_r, cnt_c, off_c);
    k_logits_fill<<<gridE, block, 0, stream>>>(k0, k1, q0, q1, ei, e_buf,
                                               cnt_r, cnt_c, eid_r, eid_c);
    k_s<<<(N_NODES * 8 + block - 1) / block, block, 0, stream>>>(e_buf, off_r, eid_r, rs);
    k_out<<<(N_NODES * 64 + block - 1) / block, block, 0, stream>>>(
        v0, v1, ei, e_buf, rs, off_c, eid_c, out0, out1);
}